// Round 13
// baseline (579.246 us; speedup 1.0000x reference)
//
#include <hip/hip_runtime.h>
#include <hip/hip_bf16.h>
#include <math.h>

// Dynamic_MHGCN_FusionLayer: B=256, N=131, IN=512, OUT=1024, H=4, D=256
// Round 13: edge_agg = R11 structure (BsL staging, no breg) + WLP=174
// conflict-free WbL stride (R12-validated) + double-buffered BsL with
// issue-early/drain-late (chunk-0 prefetched during phases 2-3; per-iter
// loads overlap MFMA). Everything else = R11.

#define LRELU(x) ((x) > 0.f ? (x) : 0.01f * (x))

constexpr int Bb = 256;
constexpr int Nn = 131;
constexpr int INF_ = 512;
constexpr int OUTF = 1024;
constexpr int Hh = 4;
constexpr int Dd = 256;
constexpr int OC = 3072;   // Gcat: Graw(0..1023) | Gk(1024..2047) | Gq(2048..3071)
constexpr int YP = 168;    // GrawT row stride (shorts)
constexpr int WLP = 174;   // WbL LDS row stride (shorts): 87 dwords, odd -> conflict-free
constexpr int KAGG = 160;  // padded K (y) for aggregation GEMM

typedef __attribute__((ext_vector_type(8))) short bf16x8;
typedef __attribute__((ext_vector_type(4))) float f32x4;

__device__ __forceinline__ float bf2f(short s) {
    union { float f; unsigned u; } c;
    c.u = ((unsigned)(unsigned short)s) << 16;
    return c.f;
}

__device__ __forceinline__ void gload_lds16(const void* g, void* lds) {
    __builtin_amdgcn_global_load_lds(
        (const __attribute__((address_space(1))) void*)g,
        (__attribute__((address_space(3))) void*)lds, 16, 0, 0);
}

// ---------------------------------------------------------------------------
// fp32 -> bf16 conversion. Wcat packed as [Wgx | Wgk | Wgq] (3072 x 512).
// ---------------------------------------------------------------------------
__global__ __launch_bounds__(256) void convert_kernel(
    const float* __restrict__ node, const float* __restrict__ Wgx,
    const float* __restrict__ Wgk, const float* __restrict__ Wgq,
    __hip_bfloat16* __restrict__ node_bf, __hip_bfloat16* __restrict__ Wcat)
{
    const size_t NE = (size_t)Bb * Nn * INF_ / 4;
    const size_t WE = (size_t)OC * INF_ / 4;
    for (size_t i = (size_t)blockIdx.x * 256 + threadIdx.x; i < NE + WE;
         i += (size_t)gridDim.x * 256) {
        if (i < NE) {
            const float4 v = ((const float4*)node)[i];
            __hip_bfloat16* o = node_bf + i * 4;
            o[0] = __float2bfloat16(v.x); o[1] = __float2bfloat16(v.y);
            o[2] = __float2bfloat16(v.z); o[3] = __float2bfloat16(v.w);
        } else {
            const size_t j = i - NE;
            const size_t which = j / (1024 * INF_ / 4);
            const float* src = (which == 0) ? Wgx : (which == 1 ? Wgk : Wgq);
            const size_t srcj = j - which * (1024 * INF_ / 4);
            const float4 v = ((const float4*)src)[srcj];
            __hip_bfloat16* o = Wcat + j * 4;
            o[0] = __float2bfloat16(v.x); o[1] = __float2bfloat16(v.y);
            o[2] = __float2bfloat16(v.z); o[3] = __float2bfloat16(v.w);
        }
    }
}

// ---------------------------------------------------------------------------
// Fused node GEMM (bf16 MFMA): 128x128 tile, 4 waves (2x2), BK=64 single
// buffer, 2 barriers/K-tile, XOR granule swizzle (0 bank conflicts),
// plain row-major stores, plain 2D grid (R9-proven).
// ---------------------------------------------------------------------------
__global__ __launch_bounds__(256, 4) void gemm_node_mfma(
    const __hip_bfloat16* __restrict__ A, const __hip_bfloat16* __restrict__ W,
    const float* __restrict__ bias_gx, __hip_bfloat16* __restrict__ Gcat)
{
    __shared__ short As[8192];   // 128 rows x 64 shorts
    __shared__ short Bs[8192];
    const int tid = threadIdx.x;
    const int wave = tid >> 6, lane = tid & 63;
    const int m0 = blockIdx.y * 128, o0 = blockIdx.x * 128;
    const int wr = wave >> 1, wc = wave & 1;

    f32x4 acc[4][4] = {};
    const short* Asrc = (const short*)A;
    const short* Wsrc = (const short*)W;
    const int gsrc = ((tid & 7) ^ ((tid >> 3) & 7)) * 8;
    const int srow = tid >> 3;

    for (int kt = 0; kt < 8; ++kt) {
        const int k0 = kt * 64;
        #pragma unroll
        for (int j = 0; j < 4; ++j) {
            const int row = j * 32 + srow;
            gload_lds16(Asrc + (size_t)(m0 + row) * INF_ + k0 + gsrc,
                        &As[(j * 256 + (tid & ~63)) * 8]);
            gload_lds16(Wsrc + (size_t)(o0 + row) * INF_ + k0 + gsrc,
                        &Bs[(j * 256 + (tid & ~63)) * 8]);
        }
        __syncthreads();
        #pragma unroll
        for (int ks = 0; ks < 2; ++ks) {
            const int sa = ((ks * 4 + (lane >> 4)) ^ (lane & 7)) * 8;
            bf16x8 af[4], bfr[4];
            #pragma unroll
            for (int i = 0; i < 4; ++i) {
                af[i]  = *(const bf16x8*)&As[(wr * 64 + i * 16 + (lane & 15)) * 64 + sa];
                bfr[i] = *(const bf16x8*)&Bs[(wc * 64 + i * 16 + (lane & 15)) * 64 + sa];
            }
            #pragma unroll
            for (int mi = 0; mi < 4; ++mi)
                #pragma unroll
                for (int ni = 0; ni < 4; ++ni)
                    acc[mi][ni] = __builtin_amdgcn_mfma_f32_16x16x32_bf16(
                        af[mi], bfr[ni], acc[mi][ni], 0, 0, 0);
        }
        __syncthreads();
    }

    const int cc = lane & 15;
    const int rg = (lane >> 4) * 4;
    #pragma unroll
    for (int mi = 0; mi < 4; ++mi)
        #pragma unroll
        for (int ni = 0; ni < 4; ++ni) {
            const int o = o0 + wc * 64 + ni * 16 + cc;
            const float badd = (o < OUTF) ? bias_gx[o] : 0.f;
            #pragma unroll
            for (int r = 0; r < 4; ++r) {
                const int m = m0 + wr * 64 + mi * 16 + rg + r;
                float v = acc[mi][ni][r] + badd;
                v = LRELU(v);
                Gcat[(size_t)m * OC + o] = __float2bfloat16(v);
            }
        }
}

// ---------------------------------------------------------------------------
// Merged tabular GEMMs (fp32): which=0 -> T_X (bias b_tx), which=1 -> T_q.
// ---------------------------------------------------------------------------
__global__ __launch_bounds__(256) void gemm_tab(
    const float* __restrict__ Atab, const float* __restrict__ Wtx,
    const float* __restrict__ btx, const float* __restrict__ Wtq,
    float* __restrict__ Ctx, float* __restrict__ Ctq)
{
    const int which = blockIdx.x >> 4;
    const float* Wm = which ? Wtq : Wtx;
    float* C = which ? Ctq : Ctx;
    __shared__ float As[16][68];
    __shared__ float Ws[16][68];
    const int tid = threadIdx.x;
    const int tx = tid & 15;
    const int ty = tid >> 4;
    const int m0 = blockIdx.y * 64;
    const int o0 = (blockIdx.x & 15) * 64;

    float acc[4][4] = {};
    for (int k0 = 0; k0 < INF_; k0 += 16) {
        const int j = tid & 15;
        const int i = tid >> 4;
        #pragma unroll
        for (int r = 0; r < 4; ++r)
            As[j][i + 16 * r] = Atab[(size_t)(m0 + i + 16 * r) * INF_ + k0 + j];
        #pragma unroll
        for (int r = 0; r < 4; ++r)
            Ws[j][i + 16 * r] = Wm[(size_t)(o0 + i + 16 * r) * INF_ + k0 + j];
        __syncthreads();
        #pragma unroll
        for (int kk = 0; kk < 16; ++kk) {
            const float4 av = *(const float4*)&As[kk][ty * 4];
            const float4 wv = *(const float4*)&Ws[kk][tx * 4];
            const float a[4] = {av.x, av.y, av.z, av.w};
            const float w[4] = {wv.x, wv.y, wv.z, wv.w};
            #pragma unroll
            for (int r = 0; r < 4; ++r)
                #pragma unroll
                for (int c = 0; c < 4; ++c)
                    acc[r][c] += a[r] * w[c];
        }
        __syncthreads();
    }
    #pragma unroll
    for (int r = 0; r < 4; ++r) {
        const int m = m0 + ty * 4 + r;
        const int o = o0 + tx * 4;
        float4 v;
        float* vp = (float*)&v;
        #pragma unroll
        for (int c = 0; c < 4; ++c) {
            float t = acc[r][c] + (which ? 0.f : btx[o + c]);
            vp[c] = LRELU(t);
        }
        *(float4*)&C[(size_t)m * OUTF + o] = v;
    }
}

// ---------------------------------------------------------------------------
// Generic fp32 tiled GEMM (final Z GEMM only).
// ---------------------------------------------------------------------------
__global__ __launch_bounds__(256) void gemm_aw(
    const float* __restrict__ A, const float* __restrict__ W,
    const float* __restrict__ bias, float* __restrict__ C,
    int M, int K, int O)
{
    __shared__ float As[16][68];
    __shared__ float Ws[16][68];
    const int tid = threadIdx.x;
    const int tx = tid & 15;
    const int ty = tid >> 4;
    const int m0 = blockIdx.y * 64;
    const int o0 = blockIdx.x * 64;

    float acc[4][4] = {};
    for (int k0 = 0; k0 < K; k0 += 16) {
        const int j = tid & 15;
        const int i = tid >> 4;
        #pragma unroll
        for (int r = 0; r < 4; ++r)
            As[j][i + 16 * r] = A[(size_t)(m0 + i + 16 * r) * K + k0 + j];
        #pragma unroll
        for (int r = 0; r < 4; ++r)
            Ws[j][i + 16 * r] = W[(size_t)(o0 + i + 16 * r) * K + k0 + j];
        __syncthreads();
        #pragma unroll
        for (int kk = 0; kk < 16; ++kk) {
            const float4 av = *(const float4*)&As[kk][ty * 4];
            const float4 wv = *(const float4*)&Ws[kk][tx * 4];
            const float a[4] = {av.x, av.y, av.z, av.w};
            const float w[4] = {wv.x, wv.y, wv.z, wv.w};
            #pragma unroll
            for (int r = 0; r < 4; ++r)
                #pragma unroll
                for (int c = 0; c < 4; ++c)
                    acc[r][c] += a[r] * w[c];
        }
        __syncthreads();
    }
    #pragma unroll
    for (int r = 0; r < 4; ++r) {
        const int m = m0 + ty * 4 + r;
        const int o = o0 + tx * 4;
        float4 v;
        float* vp = (float*)&v;
        #pragma unroll
        for (int c = 0; c < 4; ++c) {
            float t = acc[r][c] + (bias ? bias[o + c] : 0.f);
            vp[c] = LRELU(t);
        }
        *(float4*)&C[(size_t)m * O + o] = v;
    }
}

// ---------------------------------------------------------------------------
// node_att softmax: s[b,n] = (1/32) * Tq[b,:] . Gk[b,n,:]; softmax over n; +1.
// ---------------------------------------------------------------------------
__global__ __launch_bounds__(256) void nodeatt_kernel(
    const float* __restrict__ Tq, const __hip_bfloat16* __restrict__ Gcat,
    float* __restrict__ att)
{
    const int b = blockIdx.x;
    __shared__ float tq[OUTF];
    __shared__ float sc[136];
    const int tid = threadIdx.x;
    for (int o = tid; o < OUTF; o += 256) tq[o] = Tq[(size_t)b * OUTF + o];
    __syncthreads();

    const int wave = tid >> 6, lane = tid & 63;
    for (int n = wave; n < Nn; n += 4) {
        const short4* gk = (const short4*)((const short*)Gcat + ((size_t)b * Nn + n) * OC + 1024);
        float s = 0.f;
        for (int o4 = lane; o4 < 256; o4 += 64) {
            const short4 v = gk[o4];
            s += tq[o4 * 4 + 0] * bf2f(v.x) + tq[o4 * 4 + 1] * bf2f(v.y)
               + tq[o4 * 4 + 2] * bf2f(v.z) + tq[o4 * 4 + 3] * bf2f(v.w);
        }
        #pragma unroll
        for (int off = 32; off; off >>= 1) s += __shfl_xor(s, off);
        if (lane == 0) sc[n] = s * (1.f / 32.f);
    }
    __syncthreads();

    if (tid < 64) {
        const float v1 = sc[tid];
        const float v2 = sc[tid + 64];
        const float v3 = (tid < 3) ? sc[tid + 128] : -1e30f;
        float m = fmaxf(fmaxf(v1, v2), v3);
        #pragma unroll
        for (int off = 32; off; off >>= 1) m = fmaxf(m, __shfl_xor(m, off));
        const float e1 = expf(v1 - m);
        const float e2 = expf(v2 - m);
        const float e3 = (tid < 3) ? expf(v3 - m) : 0.f;
        float s = e1 + e2 + e3;
        #pragma unroll
        for (int off = 32; off; off >>= 1) s += __shfl_xor(s, off);
        const float inv = 1.f / s;
        float* ab = att + (size_t)b * Nn;
        ab[tid] = e1 * inv + 1.f;
        ab[tid + 64] = e2 * inv + 1.f;
        if (tid < 3) ab[tid + 128] = e3 * inv + 1.f;
    }
}

// ---------------------------------------------------------------------------
// Transpose Graw head-slices: GrawT[bh][d][y] (y zero-padded to 160, stride
// YP). 64x64 LDS tiles, grid (4 d-tiles, 3 y-tiles, B*H).
// ---------------------------------------------------------------------------
__global__ __launch_bounds__(256) void transpose_kernel(
    const __hip_bfloat16* __restrict__ Gcat, __hip_bfloat16* __restrict__ GrawT)
{
    const int bh = blockIdx.z, b = bh >> 2, h = bh & 3;
    const int d0 = blockIdx.x * 64, y0 = blockIdx.y * 64;
    __shared__ short Ls[64 * 72];
    const int tid = threadIdx.x;
    const short* src = (const short*)Gcat + (size_t)b * Nn * OC + h * Dd + d0;
    short* dst = (short*)GrawT + (size_t)bh * 256 * YP + (size_t)d0 * YP;

    #pragma unroll
    for (int i = 0; i < 2; ++i) {
        const int task = i * 256 + tid;
        const int r = task >> 3, c8 = task & 7;
        const int y = y0 + r;
        bf16x8 v = {};
        if (y < Nn) v = *(const bf16x8*)(src + (size_t)y * OC + c8 * 8);
        *(bf16x8*)&Ls[r * 72 + c8 * 8] = v;
    }
    __syncthreads();
    #pragma unroll
    for (int i = 0; i < 2; ++i) {
        const int task = i * 256 + tid;
        const int dr = task >> 3, y8 = task & 7;
        const int yg = y0 + y8 * 8;
        if (yg < KAGG) {
            short tmp[8];
            #pragma unroll
            for (int j = 0; j < 8; ++j) tmp[j] = Ls[(y8 * 8 + j) * 72 + dr];
            *(bf16x8*)(dst + (size_t)dr * YP + yg) = *(bf16x8*)tmp;
        }
    }
}

// ---------------------------------------------------------------------------
// edge_agg: one block (9 waves, 576 thr) per (b,h).
// Phase 1: QK^T via MFMA (Q/K dbuf staged, counted vmcnt, XOR swizzle).
// Phase 1b: issue BsL chunk-0 staging (lands by the pre-phase-4 sync).
// Phase 2: adj->regs, sigmoid, edge write, slotted rowsums, dinv.
// Phase 3: Wb -> LDS (stride WLP=174, conflict-free; y-pad zeroed).
// Phase 4: aggregation MFMA, BsL double-buffered: chunk kc+1 staged BEFORE
//          the MFMAs of chunk kc; one vmcnt(0)+barrier per iteration.
// Phase 5: Gout + gnode colsum epilogue (8 waves).
// ---------------------------------------------------------------------------
__global__ __launch_bounds__(576) void edge_agg(
    const __hip_bfloat16* __restrict__ Gcat, const float* __restrict__ adj,
    const float* __restrict__ att, const __hip_bfloat16* __restrict__ GrawT,
    const float* __restrict__ Wgs, float* __restrict__ edge,
    float* __restrict__ Gout, float* __restrict__ gnode)
{
    // SM shorts: [0,18432) Q/K dbuf (phase 1), later [0,25056) WbL.
    //            [25056, 25056+2*10240=45536) BsL double buffer.
    __shared__ short SM[45536];
    __shared__ float rsL[144 * 3];
    __shared__ float dxL[Nn], daL[Nn], attL[Nn], wgsL[Nn];

    const int bh = blockIdx.x, b = bh >> 2, h = bh & 3;
    const int tid = threadIdx.x;
    const int lane = tid & 63, wid = tid >> 6;
    const int wr = wid / 3, wc = wid % 3;
    if (tid < Nn) { attL[tid] = att[(size_t)b * Nn + tid]; wgsL[tid] = Wgs[tid]; }

    const short* qb = (const short*)Gcat + (size_t)b * Nn * OC + 2048 + h * Dd;
    const short* kb = (const short*)Gcat + (size_t)b * Nn * OC + 1024 + h * Dd;
    const short* gsrcT = (const short*)GrawT + (size_t)bh * 256 * YP;
    short* BsL = SM + 25056;

    int srow = tid >> 2; if (srow > Nn - 1) srow = Nn - 1;
    const int gsrc = ((tid & 3) ^ ((tid >> 3) & 3)) * 8;
    const int dstoff = (tid & ~63) * 8;

    auto STAGE = [&](int buf, int k0) {
        gload_lds16(qb + (size_t)srow * OC + k0 + gsrc, &SM[buf * 4608 + dstoff]);
        gload_lds16(kb + (size_t)srow * OC + k0 + gsrc, &SM[9216 + buf * 4608 + dstoff]);
    };
    // BsL staging: 1280 granules over 576 threads (<=3 per thread)
    auto STAGE_B = [&](int buf, int kc) {
        const int k0 = kc * 32;
        #pragma unroll
        for (int i = 0; i < 3; ++i) {
            const int t = i * 576 + tid;
            if (t < 1280) {
                const int row = t / 5, part = t - row * 5;
                gload_lds16(gsrcT + (size_t)row * YP + k0 + part * 8,
                            &BsL[buf * 10240 + (i * 576 + (tid & ~63)) * 8]);
            }
        }
    };

    f32x4 acc[3][3] = {};
    const int sa = ((lane >> 4) ^ ((lane >> 1) & 3)) * 8;

    STAGE(0, 0);
    for (int t = 0; t < 8; ++t) {
        const int buf = t & 1;
        if (t < 7) {
            STAGE(buf ^ 1, (t + 1) * 32);
            asm volatile("s_waitcnt vmcnt(2)" ::: "memory");
        } else {
            asm volatile("s_waitcnt vmcnt(0)" ::: "memory");
        }
        __builtin_amdgcn_s_barrier();
        __builtin_amdgcn_sched_barrier(0);
        bf16x8 qf[3], kf[3];
        #pragma unroll
        for (int i = 0; i < 3; ++i) {
            qf[i] = *(const bf16x8*)&SM[buf * 4608 + (wr * 48 + i * 16 + (lane & 15)) * 32 + sa];
            kf[i] = *(const bf16x8*)&SM[9216 + buf * 4608 + (wc * 48 + i * 16 + (lane & 15)) * 32 + sa];
        }
        __builtin_amdgcn_s_setprio(1);
        #pragma unroll
        for (int mi = 0; mi < 3; ++mi)
            #pragma unroll
            for (int ni = 0; ni < 3; ++ni)
                acc[mi][ni] = __builtin_amdgcn_mfma_f32_16x16x32_bf16(
                    qf[mi], kf[ni], acc[mi][ni], 0, 0, 0);
        __builtin_amdgcn_s_setprio(0);
        __builtin_amdgcn_sched_barrier(0);
        if (t < 7) __builtin_amdgcn_s_barrier();
    }

    // phase 1b: prefetch BsL chunk 0 (disjoint LDS region; drains by the
    // __syncthreads before phase 4).
    STAGE_B(0, 0);

    // phase 2: adj -> regs, sigmoid, edge write, slotted rowsums
    const float* adjb = adj + (size_t)b * Nn * Nn;
    float* edgeb = edge + (size_t)bh * Nn * Nn;
    const int cc = lane & 15;
    const int rg = (lane >> 4) * 4;
    float areg[3][3][4];
    #pragma unroll
    for (int mi = 0; mi < 3; ++mi) {
        float rsum[4] = {0.f, 0.f, 0.f, 0.f};
        #pragma unroll
        for (int ni = 0; ni < 3; ++ni) {
            const int y = wc * 48 + ni * 16 + cc;
            #pragma unroll
            for (int r = 0; r < 4; ++r) {
                const int x = wr * 48 + mi * 16 + rg + r;
                const bool in = (x < Nn) && (y < Nn);
                const float a = in ? adjb[x * Nn + y] : 0.f;
                areg[mi][ni][r] = a;
                const float e = 1.f / (1.f + __expf(-acc[mi][ni][r] * (1.f / 16.f)));
                acc[mi][ni][r] = e;
                if (in) {
                    edgeb[x * Nn + y] = e;
                    rsum[r] += a * e;
                }
            }
        }
        #pragma unroll
        for (int r = 0; r < 4; ++r) {
            float v = rsum[r];
            v += __shfl_xor(v, 1); v += __shfl_xor(v, 2);
            v += __shfl_xor(v, 4); v += __shfl_xor(v, 8);
            const int x = wr * 48 + mi * 16 + rg + r;
            if (cc == 0 && x < Nn) rsL[x * 3 + wc] = v;
        }
    }
    __syncthreads();
    if (tid < Nn) {
        const float s = rsL[tid * 3] + rsL[tid * 3 + 1] + rsL[tid * 3 + 2];
        const float dv = rsqrtf(s + 1.f);
        dxL[tid] = dv;
        daL[tid] = dv * attL[tid];
    }
    __syncthreads();   // Qs/Ks dead -> SM[0,25056) reusable as WbL

    // phase 3: Wb -> LDS (stride WLP). Zero y in [131,160) (only k<160 read).
    short* WbL = SM;
    for (int i = tid; i < 144 * 29; i += 576) {
        const int x = i / 29, y = 131 + i % 29;
        WbL[x * WLP + y] = 0;
    }
    #pragma unroll
    for (int mi = 0; mi < 3; ++mi)
        #pragma unroll
        for (int ni = 0; ni < 3; ++ni) {
            const int y = wc * 48 + ni * 16 + cc;
            #pragma unroll
            for (int r = 0; r < 4; ++r) {
                const int x = wr * 48 + mi * 16 + rg + r;
                if (x < Nn && y < Nn) {
                    float a = areg[mi][ni][r] * acc[mi][ni][r];
                    if (x == y) a += 1.f;
                    const float w = dxL[x] * a * daL[y];
                    __hip_bfloat16 hb = __float2bfloat16(w);
                    WbL[(size_t)x * WLP + y] = *(short*)&hb;
                }
            }
        }
    __syncthreads();   // WbL visible; BsL chunk 0 drained (vmcnt 0 at barrier)

    // phase 4: aggregation MFMA with double-buffered BsL (issue-early).
    f32x4 gacc[9][2] = {};
    for (int kc = 0; kc < 5; ++kc) {
        const int buf = kc & 1;
        if (kc < 4) STAGE_B(buf ^ 1, kc + 1);
        if (wid < 8) {
            bf16x8 af[9], bfr[2];
            #pragma unroll
            for (int mi = 0; mi < 9; ++mi)
                af[mi] = *(const bf16x8*)&WbL[(mi * 16 + (lane & 15)) * WLP + kc * 32 + (lane >> 4) * 8];
            #pragma unroll
            for (int ni = 0; ni < 2; ++ni)
                bfr[ni] = *(const bf16x8*)&BsL[buf * 10240 + (wid * 32 + ni * 16 + (lane & 15)) * 40 + (lane >> 4) * 8];
            __builtin_amdgcn_s_setprio(1);
            #pragma unroll
            for (int mi = 0; mi < 9; ++mi)
                #pragma unroll
                for (int ni = 0; ni < 2; ++ni)
                    gacc[mi][ni] = __builtin_amdgcn_mfma_f32_16x16x32_bf16(
                        af[mi], bfr[ni], gacc[mi][ni], 0, 0, 0);
            __builtin_amdgcn_s_setprio(0);
        }
        asm volatile("s_waitcnt vmcnt(0)" ::: "memory");
        __builtin_amdgcn_s_barrier();
        __builtin_amdgcn_sched_barrier(0);
    }

    // phase 5: Gout + gnode colsum (8 waves)
    if (wid < 8) {
        float* gob = Gout + (size_t)b * Nn * OUTF + h * Dd;
        float gp[2] = {0.f, 0.f};
        #pragma unroll
        for (int mi = 0; mi < 9; ++mi)
            #pragma unroll
            for (int ni = 0; ni < 2; ++ni) {
                const int d = wid * 32 + ni * 16 + (lane & 15);
                #pragma unroll
                for (int r = 0; r < 4; ++r) {
                    const int x = mi * 16 + (lane >> 4) * 4 + r;
                    if (x < Nn) {
                        gob[(size_t)x * OUTF + d] = gacc[mi][ni][r];
                        gp[ni] += wgsL[x] * gacc[mi][ni][r];
                    }
                }
            }
        #pragma unroll
        for (int ni = 0; ni < 2; ++ni) {
            gp[ni] += __shfl_xor(gp[ni], 16);
            gp[ni] += __shfl_xor(gp[ni], 32);
            if (lane < 16)
                gnode[(size_t)b * OUTF + h * Dd + wid * 32 + ni * 16 + lane] = gp[ni];
        }
    }
}

// ---------------------------------------------------------------------------
// Zin build: Zin[b][0:1024] = lrelu(gnode + bgs), Zin[b][1024:2048] = T_X.
// ---------------------------------------------------------------------------
__global__ __launch_bounds__(256) void zin_build(
    const float* __restrict__ gnode, const float* __restrict__ bgs,
    const float* __restrict__ Tx, float* __restrict__ Zin)
{
    const int idx = blockIdx.x * 256 + threadIdx.x;
    const int b = idx >> 10, o = idx & 1023;
    const float s = gnode[idx] + bgs[0];
    Zin[(size_t)b * 2048 + o] = LRELU(s);
    Zin[(size_t)b * 2048 + 1024 + o] = Tx[idx];
}

// ---------------------------------------------------------------------------
extern "C" void kernel_launch(void* const* d_in, const int* in_sizes, int n_in,
                              void* d_out, int out_size, void* d_ws, size_t ws_size,
                              hipStream_t stream) {
    const float* tab  = (const float*)d_in[0];
    const float* node = (const float*)d_in[1];
    const float* adj  = (const float*)d_in[2];
    const float* W_gx = (const float*)d_in[3];
    const float* b_gx = (const float*)d_in[4];
    const float* W_tx = (const float*)d_in[5];
    const float* b_tx = (const float*)d_in[6];
    const float* W_gk = (const float*)d_in[7];
    const float* W_tq = (const float*)d_in[8];
    const float* W_gq = (const float*)d_in[9];
    const float* W_gs = (const float*)d_in[10];
    const float* b_gs = (const float*)d_in[11];
    const float* W_zx = (const float*)d_in[12];
    const float* b_zx = (const float*)d_in[13];

    const size_t GX_ELEMS = (size_t)Bb * Nn * OUTF;   // 34,340,864
    const int M_NODE = Bb * Nn;                       // 33536

    float* out   = (float*)d_out;
    float* o_GX  = out;
    float* o_TX  = o_GX + GX_ELEMS;
    float* o_ZX  = o_TX + (size_t)Bb * OUTF;
    float* o_ATT = o_ZX + (size_t)Bb * OUTF;
    float* o_EDG = o_ATT + (size_t)Bb * Nn;

    // workspace: bf16 regions first, then fp32
    __hip_bfloat16* wb      = (__hip_bfloat16*)d_ws;
    __hip_bfloat16* w_nodeb = wb;                                          // 33536*512
    __hip_bfloat16* w_Wcat  = w_nodeb + (size_t)M_NODE * INF_;             // 3072*512
    __hip_bfloat16* w_Gcat  = w_Wcat + (size_t)OC * INF_;                  // 33536*3072
    __hip_bfloat16* w_GrawT = w_Gcat + (size_t)M_NODE * OC;                // 1024*256*168
    float* wf       = (float*)(w_GrawT + (size_t)Bb * Hh * 256 * YP);
    float* w_Tq     = wf;
    float* w_Zin    = w_Tq + (size_t)Bb * OUTF;
    float* w_gnode  = w_Zin + (size_t)Bb * 2 * OUTF;                       // 256*1024

    const dim3 blk(256);

    // 0. fp32 -> bf16 (Wcat = [Wgx | Wgk | Wgq])
    convert_kernel<<<dim3(2048), blk, 0, stream>>>(node, W_gx, W_gk, W_gq,
                                                   w_nodeb, w_Wcat);
    // 1. merged tabular GEMMs (T_X + T_q)
    gemm_tab<<<dim3(32, 4), blk, 0, stream>>>(tab, W_tx, b_tx, W_tq, o_TX, w_Tq);
    // 2. fused node GEMM -> Gcat bf16 [33536][3072] (2D grid)
    gemm_node_mfma<<<dim3(OC / 128, M_NODE / 128), blk, 0, stream>>>(
        w_nodeb, w_Wcat, b_gx, w_Gcat);
    // 3. node attention -> o_ATT (softmax + 1)
    nodeatt_kernel<<<dim3(Bb), blk, 0, stream>>>(w_Tq, w_Gcat, o_ATT);
    // 4. transpose Graw head-slices -> GrawT (zero-pads y in [131,160))
    transpose_kernel<<<dim3(4, 3, Bb * Hh), blk, 0, stream>>>(w_Gcat, w_GrawT);
    // 5. fused edge attention + rowsum + dinv + Wb(LDS) + aggregation + gn
    edge_agg<<<dim3(Bb * Hh), dim3(576), 0, stream>>>(
        w_Gcat, adj, o_ATT, w_GrawT, W_gs, o_EDG, o_GX, w_gnode);
    // 6. Zin build
    zin_build<<<dim3((Bb * OUTF) / 256), blk, 0, stream>>>(w_gnode, b_gs, o_TX, w_Zin);
    // 7. final Z GEMM
    gemm_aw<<<dim3(16, 4), blk, 0, stream>>>(w_Zin, W_zx, b_zx, o_ZX, Bb, 2 * OUTF, OUTF);
}

// Round 14
// 552.137 us; speedup vs baseline: 1.0491x; 1.0491x over previous
//
#include <hip/hip_runtime.h>
#include <hip/hip_bf16.h>
#include <math.h>

// Dynamic_MHGCN_FusionLayer: B=256, N=131, IN=512, OUT=1024, H=4, D=256
// Round 14: edge_agg = R11 base + WLP=174 (validated conflict fix) + B-operand
// read DIRECTLY from global(L2) with rolling 2-deep register prefetch
// (no BsL, no phase-4 barriers, LDS ~54 KB). Rest identical to R11/R9.

#define LRELU(x) ((x) > 0.f ? (x) : 0.01f * (x))

constexpr int Bb = 256;
constexpr int Nn = 131;
constexpr int INF_ = 512;
constexpr int OUTF = 1024;
constexpr int Hh = 4;
constexpr int Dd = 256;
constexpr int OC = 3072;   // Gcat: Graw(0..1023) | Gk(1024..2047) | Gq(2048..3071)
constexpr int YP = 168;    // GrawT row stride (shorts)
constexpr int WLP = 174;   // WbL LDS row stride (shorts): odd dword count -> conflict-free
constexpr int KAGG = 160;  // padded K (y) for aggregation GEMM

typedef __attribute__((ext_vector_type(8))) short bf16x8;
typedef __attribute__((ext_vector_type(4))) float f32x4;

__device__ __forceinline__ float bf2f(short s) {
    union { float f; unsigned u; } c;
    c.u = ((unsigned)(unsigned short)s) << 16;
    return c.f;
}

__device__ __forceinline__ void gload_lds16(const void* g, void* lds) {
    __builtin_amdgcn_global_load_lds(
        (const __attribute__((address_space(1))) void*)g,
        (__attribute__((address_space(3))) void*)lds, 16, 0, 0);
}

// ---------------------------------------------------------------------------
// fp32 -> bf16 conversion. Wcat packed as [Wgx | Wgk | Wgq] (3072 x 512).
// ---------------------------------------------------------------------------
__global__ __launch_bounds__(256) void convert_kernel(
    const float* __restrict__ node, const float* __restrict__ Wgx,
    const float* __restrict__ Wgk, const float* __restrict__ Wgq,
    __hip_bfloat16* __restrict__ node_bf, __hip_bfloat16* __restrict__ Wcat)
{
    const size_t NE = (size_t)Bb * Nn * INF_ / 4;
    const size_t WE = (size_t)OC * INF_ / 4;
    for (size_t i = (size_t)blockIdx.x * 256 + threadIdx.x; i < NE + WE;
         i += (size_t)gridDim.x * 256) {
        if (i < NE) {
            const float4 v = ((const float4*)node)[i];
            __hip_bfloat16* o = node_bf + i * 4;
            o[0] = __float2bfloat16(v.x); o[1] = __float2bfloat16(v.y);
            o[2] = __float2bfloat16(v.z); o[3] = __float2bfloat16(v.w);
        } else {
            const size_t j = i - NE;
            const size_t which = j / (1024 * INF_ / 4);
            const float* src = (which == 0) ? Wgx : (which == 1 ? Wgk : Wgq);
            const size_t srcj = j - which * (1024 * INF_ / 4);
            const float4 v = ((const float4*)src)[srcj];
            __hip_bfloat16* o = Wcat + j * 4;
            o[0] = __float2bfloat16(v.x); o[1] = __float2bfloat16(v.y);
            o[2] = __float2bfloat16(v.z); o[3] = __float2bfloat16(v.w);
        }
    }
}

// ---------------------------------------------------------------------------
// Fused node GEMM (bf16 MFMA): 128x128 tile, 4 waves (2x2), BK=64 single
// buffer, 2 barriers/K-tile, XOR granule swizzle (0 bank conflicts),
// plain row-major stores, plain 2D grid (R9-proven).
// ---------------------------------------------------------------------------
__global__ __launch_bounds__(256, 4) void gemm_node_mfma(
    const __hip_bfloat16* __restrict__ A, const __hip_bfloat16* __restrict__ W,
    const float* __restrict__ bias_gx, __hip_bfloat16* __restrict__ Gcat)
{
    __shared__ short As[8192];   // 128 rows x 64 shorts
    __shared__ short Bs[8192];
    const int tid = threadIdx.x;
    const int wave = tid >> 6, lane = tid & 63;
    const int m0 = blockIdx.y * 128, o0 = blockIdx.x * 128;
    const int wr = wave >> 1, wc = wave & 1;

    f32x4 acc[4][4] = {};
    const short* Asrc = (const short*)A;
    const short* Wsrc = (const short*)W;
    const int gsrc = ((tid & 7) ^ ((tid >> 3) & 7)) * 8;
    const int srow = tid >> 3;

    for (int kt = 0; kt < 8; ++kt) {
        const int k0 = kt * 64;
        #pragma unroll
        for (int j = 0; j < 4; ++j) {
            const int row = j * 32 + srow;
            gload_lds16(Asrc + (size_t)(m0 + row) * INF_ + k0 + gsrc,
                        &As[(j * 256 + (tid & ~63)) * 8]);
            gload_lds16(Wsrc + (size_t)(o0 + row) * INF_ + k0 + gsrc,
                        &Bs[(j * 256 + (tid & ~63)) * 8]);
        }
        __syncthreads();
        #pragma unroll
        for (int ks = 0; ks < 2; ++ks) {
            const int sa = ((ks * 4 + (lane >> 4)) ^ (lane & 7)) * 8;
            bf16x8 af[4], bfr[4];
            #pragma unroll
            for (int i = 0; i < 4; ++i) {
                af[i]  = *(const bf16x8*)&As[(wr * 64 + i * 16 + (lane & 15)) * 64 + sa];
                bfr[i] = *(const bf16x8*)&Bs[(wc * 64 + i * 16 + (lane & 15)) * 64 + sa];
            }
            #pragma unroll
            for (int mi = 0; mi < 4; ++mi)
                #pragma unroll
                for (int ni = 0; ni < 4; ++ni)
                    acc[mi][ni] = __builtin_amdgcn_mfma_f32_16x16x32_bf16(
                        af[mi], bfr[ni], acc[mi][ni], 0, 0, 0);
        }
        __syncthreads();
    }

    const int cc = lane & 15;
    const int rg = (lane >> 4) * 4;
    #pragma unroll
    for (int mi = 0; mi < 4; ++mi)
        #pragma unroll
        for (int ni = 0; ni < 4; ++ni) {
            const int o = o0 + wc * 64 + ni * 16 + cc;
            const float badd = (o < OUTF) ? bias_gx[o] : 0.f;
            #pragma unroll
            for (int r = 0; r < 4; ++r) {
                const int m = m0 + wr * 64 + mi * 16 + rg + r;
                float v = acc[mi][ni][r] + badd;
                v = LRELU(v);
                Gcat[(size_t)m * OC + o] = __float2bfloat16(v);
            }
        }
}

// ---------------------------------------------------------------------------
// Merged tabular GEMMs (fp32): which=0 -> T_X (bias b_tx), which=1 -> T_q.
// ---------------------------------------------------------------------------
__global__ __launch_bounds__(256) void gemm_tab(
    const float* __restrict__ Atab, const float* __restrict__ Wtx,
    const float* __restrict__ btx, const float* __restrict__ Wtq,
    float* __restrict__ Ctx, float* __restrict__ Ctq)
{
    const int which = blockIdx.x >> 4;
    const float* Wm = which ? Wtq : Wtx;
    float* C = which ? Ctq : Ctx;
    __shared__ float As[16][68];
    __shared__ float Ws[16][68];
    const int tid = threadIdx.x;
    const int tx = tid & 15;
    const int ty = tid >> 4;
    const int m0 = blockIdx.y * 64;
    const int o0 = (blockIdx.x & 15) * 64;

    float acc[4][4] = {};
    for (int k0 = 0; k0 < INF_; k0 += 16) {
        const int j = tid & 15;
        const int i = tid >> 4;
        #pragma unroll
        for (int r = 0; r < 4; ++r)
            As[j][i + 16 * r] = Atab[(size_t)(m0 + i + 16 * r) * INF_ + k0 + j];
        #pragma unroll
        for (int r = 0; r < 4; ++r)
            Ws[j][i + 16 * r] = Wm[(size_t)(o0 + i + 16 * r) * INF_ + k0 + j];
        __syncthreads();
        #pragma unroll
        for (int kk = 0; kk < 16; ++kk) {
            const float4 av = *(const float4*)&As[kk][ty * 4];
            const float4 wv = *(const float4*)&Ws[kk][tx * 4];
            const float a[4] = {av.x, av.y, av.z, av.w};
            const float w[4] = {wv.x, wv.y, wv.z, wv.w};
            #pragma unroll
            for (int r = 0; r < 4; ++r)
                #pragma unroll
                for (int c = 0; c < 4; ++c)
                    acc[r][c] += a[r] * w[c];
        }
        __syncthreads();
    }
    #pragma unroll
    for (int r = 0; r < 4; ++r) {
        const int m = m0 + ty * 4 + r;
        const int o = o0 + tx * 4;
        float4 v;
        float* vp = (float*)&v;
        #pragma unroll
        for (int c = 0; c < 4; ++c) {
            float t = acc[r][c] + (which ? 0.f : btx[o + c]);
            vp[c] = LRELU(t);
        }
        *(float4*)&C[(size_t)m * OUTF + o] = v;
    }
}

// ---------------------------------------------------------------------------
// Generic fp32 tiled GEMM (final Z GEMM only).
// ---------------------------------------------------------------------------
__global__ __launch_bounds__(256) void gemm_aw(
    const float* __restrict__ A, const float* __restrict__ W,
    const float* __restrict__ bias, float* __restrict__ C,
    int M, int K, int O)
{
    __shared__ float As[16][68];
    __shared__ float Ws[16][68];
    const int tid = threadIdx.x;
    const int tx = tid & 15;
    const int ty = tid >> 4;
    const int m0 = blockIdx.y * 64;
    const int o0 = blockIdx.x * 64;

    float acc[4][4] = {};
    for (int k0 = 0; k0 < K; k0 += 16) {
        const int j = tid & 15;
        const int i = tid >> 4;
        #pragma unroll
        for (int r = 0; r < 4; ++r)
            As[j][i + 16 * r] = A[(size_t)(m0 + i + 16 * r) * K + k0 + j];
        #pragma unroll
        for (int r = 0; r < 4; ++r)
            Ws[j][i + 16 * r] = W[(size_t)(o0 + i + 16 * r) * K + k0 + j];
        __syncthreads();
        #pragma unroll
        for (int kk = 0; kk < 16; ++kk) {
            const float4 av = *(const float4*)&As[kk][ty * 4];
            const float4 wv = *(const float4*)&Ws[kk][tx * 4];
            const float a[4] = {av.x, av.y, av.z, av.w};
            const float w[4] = {wv.x, wv.y, wv.z, wv.w};
            #pragma unroll
            for (int r = 0; r < 4; ++r)
                #pragma unroll
                for (int c = 0; c < 4; ++c)
                    acc[r][c] += a[r] * w[c];
        }
        __syncthreads();
    }
    #pragma unroll
    for (int r = 0; r < 4; ++r) {
        const int m = m0 + ty * 4 + r;
        const int o = o0 + tx * 4;
        float4 v;
        float* vp = (float*)&v;
        #pragma unroll
        for (int c = 0; c < 4; ++c) {
            float t = acc[r][c] + (bias ? bias[o + c] : 0.f);
            vp[c] = LRELU(t);
        }
        *(float4*)&C[(size_t)m * O + o] = v;
    }
}

// ---------------------------------------------------------------------------
// node_att softmax: s[b,n] = (1/32) * Tq[b,:] . Gk[b,n,:]; softmax over n; +1.
// ---------------------------------------------------------------------------
__global__ __launch_bounds__(256) void nodeatt_kernel(
    const float* __restrict__ Tq, const __hip_bfloat16* __restrict__ Gcat,
    float* __restrict__ att)
{
    const int b = blockIdx.x;
    __shared__ float tq[OUTF];
    __shared__ float sc[136];
    const int tid = threadIdx.x;
    for (int o = tid; o < OUTF; o += 256) tq[o] = Tq[(size_t)b * OUTF + o];
    __syncthreads();

    const int wave = tid >> 6, lane = tid & 63;
    for (int n = wave; n < Nn; n += 4) {
        const short4* gk = (const short4*)((const short*)Gcat + ((size_t)b * Nn + n) * OC + 1024);
        float s = 0.f;
        for (int o4 = lane; o4 < 256; o4 += 64) {
            const short4 v = gk[o4];
            s += tq[o4 * 4 + 0] * bf2f(v.x) + tq[o4 * 4 + 1] * bf2f(v.y)
               + tq[o4 * 4 + 2] * bf2f(v.z) + tq[o4 * 4 + 3] * bf2f(v.w);
        }
        #pragma unroll
        for (int off = 32; off; off >>= 1) s += __shfl_xor(s, off);
        if (lane == 0) sc[n] = s * (1.f / 32.f);
    }
    __syncthreads();

    if (tid < 64) {
        const float v1 = sc[tid];
        const float v2 = sc[tid + 64];
        const float v3 = (tid < 3) ? sc[tid + 128] : -1e30f;
        float m = fmaxf(fmaxf(v1, v2), v3);
        #pragma unroll
        for (int off = 32; off; off >>= 1) m = fmaxf(m, __shfl_xor(m, off));
        const float e1 = expf(v1 - m);
        const float e2 = expf(v2 - m);
        const float e3 = (tid < 3) ? expf(v3 - m) : 0.f;
        float s = e1 + e2 + e3;
        #pragma unroll
        for (int off = 32; off; off >>= 1) s += __shfl_xor(s, off);
        const float inv = 1.f / s;
        float* ab = att + (size_t)b * Nn;
        ab[tid] = e1 * inv + 1.f;
        ab[tid + 64] = e2 * inv + 1.f;
        if (tid < 3) ab[tid + 128] = e3 * inv + 1.f;
    }
}

// ---------------------------------------------------------------------------
// Transpose Graw head-slices: GrawT[bh][d][y] (y zero-padded to 160, stride
// YP). 64x64 LDS tiles, grid (4 d-tiles, 3 y-tiles, B*H).
// ---------------------------------------------------------------------------
__global__ __launch_bounds__(256) void transpose_kernel(
    const __hip_bfloat16* __restrict__ Gcat, __hip_bfloat16* __restrict__ GrawT)
{
    const int bh = blockIdx.z, b = bh >> 2, h = bh & 3;
    const int d0 = blockIdx.x * 64, y0 = blockIdx.y * 64;
    __shared__ short Ls[64 * 72];
    const int tid = threadIdx.x;
    const short* src = (const short*)Gcat + (size_t)b * Nn * OC + h * Dd + d0;
    short* dst = (short*)GrawT + (size_t)bh * 256 * YP + (size_t)d0 * YP;

    #pragma unroll
    for (int i = 0; i < 2; ++i) {
        const int task = i * 256 + tid;
        const int r = task >> 3, c8 = task & 7;
        const int y = y0 + r;
        bf16x8 v = {};
        if (y < Nn) v = *(const bf16x8*)(src + (size_t)y * OC + c8 * 8);
        *(bf16x8*)&Ls[r * 72 + c8 * 8] = v;
    }
    __syncthreads();
    #pragma unroll
    for (int i = 0; i < 2; ++i) {
        const int task = i * 256 + tid;
        const int dr = task >> 3, y8 = task & 7;
        const int yg = y0 + y8 * 8;
        if (yg < KAGG) {
            short tmp[8];
            #pragma unroll
            for (int j = 0; j < 8; ++j) tmp[j] = Ls[(y8 * 8 + j) * 72 + dr];
            *(bf16x8*)(dst + (size_t)dr * YP + yg) = *(bf16x8*)tmp;
        }
    }
}

// ---------------------------------------------------------------------------
// edge_agg: one block (9 waves, 576 thr) per (b,h).
// Phase 1: QK^T via MFMA (Q/K dbuf staged, counted vmcnt, XOR swizzle).
// Phase 2: adj->regs, sigmoid, edge write, slotted rowsums, dinv.
// Phase 2b: prefetch chunk-0 B-fragments (global->reg; Wb build hides L2 lat).
// Phase 3: Wb -> LDS (stride WLP=174, conflict-free; y-pad zeroed).
// Phase 4: aggregation MFMA — af from WbL (ds_read), bfr from global with
//          rolling 2-deep register prefetch. NO barriers, NO B staging LDS.
// Phase 5: Gout + gnode colsum epilogue (8 waves).
// ---------------------------------------------------------------------------
__global__ __launch_bounds__(576) void edge_agg(
    const __hip_bfloat16* __restrict__ Gcat, const float* __restrict__ adj,
    const float* __restrict__ att, const __hip_bfloat16* __restrict__ GrawT,
    const float* __restrict__ Wgs, float* __restrict__ edge,
    float* __restrict__ Gout, float* __restrict__ gnode)
{
    // SM shorts: phase 1 uses [0,18432) (Q/K dbuf); phase 3/4 uses
    // [0, 144*174=25056) as WbL. Total LDS ~54 KB.
    __shared__ short SM[25056];
    __shared__ float rsL[144 * 3];
    __shared__ float dxL[Nn], daL[Nn], attL[Nn], wgsL[Nn];

    const int bh = blockIdx.x, b = bh >> 2, h = bh & 3;
    const int tid = threadIdx.x;
    const int lane = tid & 63, wid = tid >> 6;
    const int wr = wid / 3, wc = wid % 3;
    if (tid < Nn) { attL[tid] = att[(size_t)b * Nn + tid]; wgsL[tid] = Wgs[tid]; }

    const short* qb = (const short*)Gcat + (size_t)b * Nn * OC + 2048 + h * Dd;
    const short* kb = (const short*)Gcat + (size_t)b * Nn * OC + 1024 + h * Dd;
    const short* gsrcT = (const short*)GrawT + (size_t)bh * 256 * YP;

    int srow = tid >> 2; if (srow > Nn - 1) srow = Nn - 1;
    const int gsrc = ((tid & 3) ^ ((tid >> 3) & 3)) * 8;
    const int dstoff = (tid & ~63) * 8;

    auto STAGE = [&](int buf, int k0) {
        gload_lds16(qb + (size_t)srow * OC + k0 + gsrc, &SM[buf * 4608 + dstoff]);
        gload_lds16(kb + (size_t)srow * OC + k0 + gsrc, &SM[9216 + buf * 4608 + dstoff]);
    };

    f32x4 acc[3][3] = {};
    const int sa = ((lane >> 4) ^ ((lane >> 1) & 3)) * 8;

    STAGE(0, 0);
    for (int t = 0; t < 8; ++t) {
        const int buf = t & 1;
        if (t < 7) {
            STAGE(buf ^ 1, (t + 1) * 32);
            asm volatile("s_waitcnt vmcnt(2)" ::: "memory");
        } else {
            asm volatile("s_waitcnt vmcnt(0)" ::: "memory");
        }
        __builtin_amdgcn_s_barrier();
        __builtin_amdgcn_sched_barrier(0);
        bf16x8 qf[3], kf[3];
        #pragma unroll
        for (int i = 0; i < 3; ++i) {
            qf[i] = *(const bf16x8*)&SM[buf * 4608 + (wr * 48 + i * 16 + (lane & 15)) * 32 + sa];
            kf[i] = *(const bf16x8*)&SM[9216 + buf * 4608 + (wc * 48 + i * 16 + (lane & 15)) * 32 + sa];
        }
        __builtin_amdgcn_s_setprio(1);
        #pragma unroll
        for (int mi = 0; mi < 3; ++mi)
            #pragma unroll
            for (int ni = 0; ni < 3; ++ni)
                acc[mi][ni] = __builtin_amdgcn_mfma_f32_16x16x32_bf16(
                    qf[mi], kf[ni], acc[mi][ni], 0, 0, 0);
        __builtin_amdgcn_s_setprio(0);
        __builtin_amdgcn_sched_barrier(0);
        if (t < 7) __builtin_amdgcn_s_barrier();
    }

    // phase 2: adj -> regs, sigmoid, edge write, slotted rowsums
    const float* adjb = adj + (size_t)b * Nn * Nn;
    float* edgeb = edge + (size_t)bh * Nn * Nn;
    const int cc = lane & 15;
    const int rg = (lane >> 4) * 4;
    float areg[3][3][4];
    #pragma unroll
    for (int mi = 0; mi < 3; ++mi) {
        float rsum[4] = {0.f, 0.f, 0.f, 0.f};
        #pragma unroll
        for (int ni = 0; ni < 3; ++ni) {
            const int y = wc * 48 + ni * 16 + cc;
            #pragma unroll
            for (int r = 0; r < 4; ++r) {
                const int x = wr * 48 + mi * 16 + rg + r;
                const bool in = (x < Nn) && (y < Nn);
                const float a = in ? adjb[x * Nn + y] : 0.f;
                areg[mi][ni][r] = a;
                const float e = 1.f / (1.f + __expf(-acc[mi][ni][r] * (1.f / 16.f)));
                acc[mi][ni][r] = e;
                if (in) {
                    edgeb[x * Nn + y] = e;
                    rsum[r] += a * e;
                }
            }
        }
        #pragma unroll
        for (int r = 0; r < 4; ++r) {
            float v = rsum[r];
            v += __shfl_xor(v, 1); v += __shfl_xor(v, 2);
            v += __shfl_xor(v, 4); v += __shfl_xor(v, 8);
            const int x = wr * 48 + mi * 16 + rg + r;
            if (cc == 0 && x < Nn) rsL[x * 3 + wc] = v;
        }
    }
    __syncthreads();
    if (tid < Nn) {
        const float s = rsL[tid * 3] + rsL[tid * 3 + 1] + rsL[tid * 3 + 2];
        const float dv = rsqrtf(s + 1.f);
        dxL[tid] = dv;
        daL[tid] = dv * attL[tid];
    }
    __syncthreads();   // Qs/Ks dead -> SM reusable as WbL

    // phase 2b: prefetch chunk-0 B-fragments (L2-resident GrawT); the Wb
    // build below covers the load latency.
    const int brow0 = wid * 32 + (lane & 15);       // ni=0 row
    const int bcol = (lane >> 4) * 8;
    bf16x8 bcur0, bcur1;
    if (wid < 8) {
        bcur0 = *(const bf16x8*)&gsrcT[(size_t)brow0 * YP + 0 + bcol];
        bcur1 = *(const bf16x8*)&gsrcT[(size_t)(brow0 + 16) * YP + 0 + bcol];
    }

    // phase 3: Wb -> LDS (stride WLP). Zero y in [131,160) (only k<160 read).
    short* WbL = SM;
    for (int i = tid; i < 144 * 29; i += 576) {
        const int x = i / 29, y = 131 + i % 29;
        WbL[x * WLP + y] = 0;
    }
    #pragma unroll
    for (int mi = 0; mi < 3; ++mi)
        #pragma unroll
        for (int ni = 0; ni < 3; ++ni) {
            const int y = wc * 48 + ni * 16 + cc;
            #pragma unroll
            for (int r = 0; r < 4; ++r) {
                const int x = wr * 48 + mi * 16 + rg + r;
                if (x < Nn && y < Nn) {
                    float a = areg[mi][ni][r] * acc[mi][ni][r];
                    if (x == y) a += 1.f;
                    const float w = dxL[x] * a * daL[y];
                    __hip_bfloat16 hb = __float2bfloat16(w);
                    WbL[(size_t)x * WLP + y] = *(short*)&hb;
                }
            }
        }
    __syncthreads();   // WbL visible to all waves

    // phase 4: aggregation MFMA — af from WbL, bfr rolling register prefetch.
    if (wid < 8) {
        f32x4 gacc[9][2] = {};
        #pragma unroll
        for (int kc = 0; kc < 5; ++kc) {
            bf16x8 bnxt0, bnxt1;
            if (kc < 4) {
                bnxt0 = *(const bf16x8*)&gsrcT[(size_t)brow0 * YP + (kc + 1) * 32 + bcol];
                bnxt1 = *(const bf16x8*)&gsrcT[(size_t)(brow0 + 16) * YP + (kc + 1) * 32 + bcol];
            }
            bf16x8 af[9];
            #pragma unroll
            for (int mi = 0; mi < 9; ++mi)
                af[mi] = *(const bf16x8*)&WbL[(mi * 16 + (lane & 15)) * WLP + kc * 32 + (lane >> 4) * 8];
            __builtin_amdgcn_s_setprio(1);
            #pragma unroll
            for (int mi = 0; mi < 9; ++mi) {
                gacc[mi][0] = __builtin_amdgcn_mfma_f32_16x16x32_bf16(
                    af[mi], bcur0, gacc[mi][0], 0, 0, 0);
                gacc[mi][1] = __builtin_amdgcn_mfma_f32_16x16x32_bf16(
                    af[mi], bcur1, gacc[mi][1], 0, 0, 0);
            }
            __builtin_amdgcn_s_setprio(0);
            if (kc < 4) { bcur0 = bnxt0; bcur1 = bnxt1; }
        }

        // phase 5: Gout + gnode colsum (8 waves)
        float* gob = Gout + (size_t)b * Nn * OUTF + h * Dd;
        float gp[2] = {0.f, 0.f};
        #pragma unroll
        for (int mi = 0; mi < 9; ++mi)
            #pragma unroll
            for (int ni = 0; ni < 2; ++ni) {
                const int d = wid * 32 + ni * 16 + (lane & 15);
                #pragma unroll
                for (int r = 0; r < 4; ++r) {
                    const int x = mi * 16 + (lane >> 4) * 4 + r;
                    if (x < Nn) {
                        gob[(size_t)x * OUTF + d] = gacc[mi][ni][r];
                        gp[ni] += wgsL[x] * gacc[mi][ni][r];
                    }
                }
            }
        #pragma unroll
        for (int ni = 0; ni < 2; ++ni) {
            gp[ni] += __shfl_xor(gp[ni], 16);
            gp[ni] += __shfl_xor(gp[ni], 32);
            if (lane < 16)
                gnode[(size_t)b * OUTF + h * Dd + wid * 32 + ni * 16 + lane] = gp[ni];
        }
    }
}

// ---------------------------------------------------------------------------
// Zin build: Zin[b][0:1024] = lrelu(gnode + bgs), Zin[b][1024:2048] = T_X.
// ---------------------------------------------------------------------------
__global__ __launch_bounds__(256) void zin_build(
    const float* __restrict__ gnode, const float* __restrict__ bgs,
    const float* __restrict__ Tx, float* __restrict__ Zin)
{
    const int idx = blockIdx.x * 256 + threadIdx.x;
    const int b = idx >> 10, o = idx & 1023;
    const float s = gnode[idx] + bgs[0];
    Zin[(size_t)b * 2048 + o] = LRELU(s);
    Zin[(size_t)b * 2048 + 1024 + o] = Tx[idx];
}

// ---------------------------------------------------------------------------
extern "C" void kernel_launch(void* const* d_in, const int* in_sizes, int n_in,
                              void* d_out, int out_size, void* d_ws, size_t ws_size,
                              hipStream_t stream) {
    const float* tab  = (const float*)d_in[0];
    const float* node = (const float*)d_in[1];
    const float* adj  = (const float*)d_in[2];
    const float* W_gx = (const float*)d_in[3];
    const float* b_gx = (const float*)d_in[4];
    const float* W_tx = (const float*)d_in[5];
    const float* b_tx = (const float*)d_in[6];
    const float* W_gk = (const float*)d_in[7];
    const float* W_tq = (const float*)d_in[8];
    const float* W_gq = (const float*)d_in[9];
    const float* W_gs = (const float*)d_in[10];
    const float* b_gs = (const float*)d_in[11];
    const float* W_zx = (const float*)d_in[12];
    const float* b_zx = (const float*)d_in[13];

    const size_t GX_ELEMS = (size_t)Bb * Nn * OUTF;   // 34,340,864
    const int M_NODE = Bb * Nn;                       // 33536

    float* out   = (float*)d_out;
    float* o_GX  = out;
    float* o_TX  = o_GX + GX_ELEMS;
    float* o_ZX  = o_TX + (size_t)Bb * OUTF;
    float* o_ATT = o_ZX + (size_t)Bb * OUTF;
    float* o_EDG = o_ATT + (size_t)Bb * Nn;

    // workspace: bf16 regions first, then fp32
    __hip_bfloat16* wb      = (__hip_bfloat16*)d_ws;
    __hip_bfloat16* w_nodeb = wb;                                          // 33536*512
    __hip_bfloat16* w_Wcat  = w_nodeb + (size_t)M_NODE * INF_;             // 3072*512
    __hip_bfloat16* w_Gcat  = w_Wcat + (size_t)OC * INF_;                  // 33536*3072
    __hip_bfloat16* w_GrawT = w_Gcat + (size_t)M_NODE * OC;                // 1024*256*168
    float* wf       = (float*)(w_GrawT + (size_t)Bb * Hh * 256 * YP);
    float* w_Tq     = wf;
    float* w_Zin    = w_Tq + (size_t)Bb * OUTF;
    float* w_gnode  = w_Zin + (size_t)Bb * 2 * OUTF;                       // 256*1024

    const dim3 blk(256);

    // 0. fp32 -> bf16 (Wcat = [Wgx | Wgk | Wgq])
    convert_kernel<<<dim3(2048), blk, 0, stream>>>(node, W_gx, W_gk, W_gq,
                                                   w_nodeb, w_Wcat);
    // 1. merged tabular GEMMs (T_X + T_q)
    gemm_tab<<<dim3(32, 4), blk, 0, stream>>>(tab, W_tx, b_tx, W_tq, o_TX, w_Tq);
    // 2. fused node GEMM -> Gcat bf16 [33536][3072] (2D grid)
    gemm_node_mfma<<<dim3(OC / 128, M_NODE / 128), blk, 0, stream>>>(
        w_nodeb, w_Wcat, b_gx, w_Gcat);
    // 3. node attention -> o_ATT (softmax + 1)
    nodeatt_kernel<<<dim3(Bb), blk, 0, stream>>>(w_Tq, w_Gcat, o_ATT);
    // 4. transpose Graw head-slices -> GrawT (zero-pads y in [131,160))
    transpose_kernel<<<dim3(4, 3, Bb * Hh), blk, 0, stream>>>(w_Gcat, w_GrawT);
    // 5. fused edge attention + rowsum + dinv + Wb(LDS) + aggregation + gn
    edge_agg<<<dim3(Bb * Hh), dim3(576), 0, stream>>>(
        w_Gcat, adj, o_ATT, w_GrawT, W_gs, o_EDG, o_GX, w_gnode);
    // 6. Zin build
    zin_build<<<dim3((Bb * OUTF) / 256), blk, 0, stream>>>(w_gnode, b_gs, o_TX, w_Zin);
    // 7. final Z GEMM
    gemm_aw<<<dim3(16, 4), blk, 0, stream>>>(w_Zin, W_zx, b_zx, o_ZX, Bb, 2 * OUTF, OUTF);
}

// Round 15
// 532.400 us; speedup vs baseline: 1.0880x; 1.0371x over previous
//
#include <hip/hip_runtime.h>
#include <hip/hip_bf16.h>
#include <math.h>

// Dynamic_MHGCN_FusionLayer: B=256, N=131, IN=512, OUT=1024, H=4, D=256
// Round 15: transpose kernel eliminated — gemm_node writes Graw o-tiles
// directly transposed to GrawT via an LDS-staged COALESCED epilogue (16B
// stores; not R8's 2B scatter). Gcat shrinks to [M][2048] = Gk|Gq.
// Wcat = [Wgk|Wgq|Wgx]. edge_agg = R14 (best known, 197us).

#define LRELU(x) ((x) > 0.f ? (x) : 0.01f * (x))

constexpr int Bb = 256;
constexpr int Nn = 131;
constexpr int INF_ = 512;
constexpr int OUTF = 1024;
constexpr int Hh = 4;
constexpr int Dd = 256;
constexpr int OC2 = 2048;  // Gcat: Gk(0..1023) | Gq(1024..2047)
constexpr int YP = 168;    // GrawT row stride (shorts)
constexpr int WLP = 174;   // WbL LDS row stride (shorts): odd dword count -> conflict-free
constexpr int KAGG = 160;  // padded K (y) for aggregation GEMM

typedef __attribute__((ext_vector_type(8))) short bf16x8;
typedef __attribute__((ext_vector_type(4))) float f32x4;

__device__ __forceinline__ float bf2f(short s) {
    union { float f; unsigned u; } c;
    c.u = ((unsigned)(unsigned short)s) << 16;
    return c.f;
}

__device__ __forceinline__ void gload_lds16(const void* g, void* lds) {
    __builtin_amdgcn_global_load_lds(
        (const __attribute__((address_space(1))) void*)g,
        (__attribute__((address_space(3))) void*)lds, 16, 0, 0);
}

// ---------------------------------------------------------------------------
// fp32 -> bf16 conversion. Wcat packed as [Wgk | Wgq | Wgx] (3072 x 512).
// ---------------------------------------------------------------------------
__global__ __launch_bounds__(256) void convert_kernel(
    const float* __restrict__ node, const float* __restrict__ Wgx,
    const float* __restrict__ Wgk, const float* __restrict__ Wgq,
    __hip_bfloat16* __restrict__ node_bf, __hip_bfloat16* __restrict__ Wcat)
{
    const size_t NE = (size_t)Bb * Nn * INF_ / 4;
    const size_t WE = (size_t)3072 * INF_ / 4;
    for (size_t i = (size_t)blockIdx.x * 256 + threadIdx.x; i < NE + WE;
         i += (size_t)gridDim.x * 256) {
        if (i < NE) {
            const float4 v = ((const float4*)node)[i];
            __hip_bfloat16* o = node_bf + i * 4;
            o[0] = __float2bfloat16(v.x); o[1] = __float2bfloat16(v.y);
            o[2] = __float2bfloat16(v.z); o[3] = __float2bfloat16(v.w);
        } else {
            const size_t j = i - NE;
            const size_t which = j / (1024 * INF_ / 4);
            const float* src = (which == 0) ? Wgk : (which == 1 ? Wgq : Wgx);
            const size_t srcj = j - which * (1024 * INF_ / 4);
            const float4 v = ((const float4*)src)[srcj];
            __hip_bfloat16* o = Wcat + j * 4;
            o[0] = __float2bfloat16(v.x); o[1] = __float2bfloat16(v.y);
            o[2] = __float2bfloat16(v.z); o[3] = __float2bfloat16(v.w);
        }
    }
}

// ---------------------------------------------------------------------------
// Fused node GEMM (bf16 MFMA): 128x128 tile, 4 waves (2x2), BK=64 single
// buffer, 2 barriers/K-tile, XOR granule swizzle (0 bank conflicts).
// o-tiles 0..15 (Gk|Gq): row-major stores to Gcat [M][2048], no bias.
// o-tiles 16..23 (Graw): lrelu(.+b_gx), TRANSPOSED via LDS staging ->
// coalesced 16B stores to GrawT[(b*4+h)*256+d][n].
// ---------------------------------------------------------------------------
__global__ __launch_bounds__(256, 4) void gemm_node_mfma(
    const __hip_bfloat16* __restrict__ A, const __hip_bfloat16* __restrict__ W,
    const float* __restrict__ bias_gx, __hip_bfloat16* __restrict__ Gcat,
    __hip_bfloat16* __restrict__ GrawT)
{
    __shared__ short SM[16384];          // As=[0,8192), Bs=[8192,16384)
    short* As = SM;
    short* Bs = SM + 8192;
    const int tid = threadIdx.x;
    const int wave = tid >> 6, lane = tid & 63;
    const int m0 = blockIdx.y * 128, o0 = blockIdx.x * 128;
    const int wr = wave >> 1, wc = wave & 1;

    f32x4 acc[4][4] = {};
    const short* Asrc = (const short*)A;
    const short* Wsrc = (const short*)W;
    const int gsrc = ((tid & 7) ^ ((tid >> 3) & 7)) * 8;
    const int srow = tid >> 3;

    for (int kt = 0; kt < 8; ++kt) {
        const int k0 = kt * 64;
        #pragma unroll
        for (int j = 0; j < 4; ++j) {
            const int row = j * 32 + srow;
            gload_lds16(Asrc + (size_t)(m0 + row) * INF_ + k0 + gsrc,
                        &As[(j * 256 + (tid & ~63)) * 8]);
            gload_lds16(Wsrc + (size_t)(o0 + row) * INF_ + k0 + gsrc,
                        &Bs[(j * 256 + (tid & ~63)) * 8]);
        }
        __syncthreads();
        #pragma unroll
        for (int ks = 0; ks < 2; ++ks) {
            const int sa = ((ks * 4 + (lane >> 4)) ^ (lane & 7)) * 8;
            bf16x8 af[4], bfr[4];
            #pragma unroll
            for (int i = 0; i < 4; ++i) {
                af[i]  = *(const bf16x8*)&As[(wr * 64 + i * 16 + (lane & 15)) * 64 + sa];
                bfr[i] = *(const bf16x8*)&Bs[(wc * 64 + i * 16 + (lane & 15)) * 64 + sa];
            }
            #pragma unroll
            for (int mi = 0; mi < 4; ++mi)
                #pragma unroll
                for (int ni = 0; ni < 4; ++ni)
                    acc[mi][ni] = __builtin_amdgcn_mfma_f32_16x16x32_bf16(
                        af[mi], bfr[ni], acc[mi][ni], 0, 0, 0);
        }
        __syncthreads();
    }

    const int cc = lane & 15;
    const int rg = (lane >> 4) * 4;
    if (o0 < OC2) {
        // Gk|Gq: lrelu, row-major scalar stores (R9-proven path)
        #pragma unroll
        for (int mi = 0; mi < 4; ++mi)
            #pragma unroll
            for (int ni = 0; ni < 4; ++ni) {
                const int o = o0 + wc * 64 + ni * 16 + cc;
                #pragma unroll
                for (int r = 0; r < 4; ++r) {
                    const int m = m0 + wr * 64 + mi * 16 + rg + r;
                    float v = acc[mi][ni][r];
                    v = LRELU(v);
                    Gcat[(size_t)m * OC2 + o] = __float2bfloat16(v);
                }
            }
    } else {
        // Graw tile: lrelu(.+b_gx); stage transposed in SM with XOR-granule
        // swizzle, then coalesced 16B stores to GrawT.
        const int og0 = o0 - OC2;          // tile base within Graw cols
        const int h = og0 >> 8;            // head (tile is 128-aligned -> fixed)
        const int dbase = og0 & 255;
        __syncthreads();                   // K-loop LDS reads done, SM reusable
        #pragma unroll
        for (int mi = 0; mi < 4; ++mi)
            #pragma unroll
            for (int ni = 0; ni < 4; ++ni) {
                const int dloc = wc * 64 + ni * 16 + cc;
                const float badd = bias_gx[og0 + dloc];
                #pragma unroll
                for (int r = 0; r < 4; ++r) {
                    const int row = wr * 64 + mi * 16 + rg + r;
                    float v = acc[mi][ni][r] + badd;
                    v = LRELU(v);
                    __hip_bfloat16 hb = __float2bfloat16(v);
                    const int g = row >> 3;
                    SM[dloc * 128 + ((g ^ (dloc & 7)) << 3) + (row & 7)] = *(short*)&hb;
                }
            }
        __syncthreads();
        short* GT = (short*)GrawT;
        #pragma unroll
        for (int j = 0; j < 8; ++j) {
            const int task = j * 256 + tid;        // 2048 tasks
            const int dloc = task >> 4;            // 0..127
            const int g = task & 15;               // row granule
            const bf16x8 v = *(const bf16x8*)&SM[dloc * 128 + ((g ^ (dloc & 7)) << 3)];
            const int m = m0 + g * 8;
            const int gd = dbase + dloc;
            const int b0 = m / 131;
            const int n0 = m - b0 * 131;
            if (n0 + 8 <= Nn) {
                *(bf16x8*)&GT[((size_t)(b0 * Hh + h) * 256 + gd) * YP + n0] = v;
            } else {
                #pragma unroll
                for (int e = 0; e < 8; ++e) {
                    const int mm = m + e;
                    const int bb = mm / 131;
                    const int nn = mm - bb * 131;
                    GT[((size_t)(bb * Hh + h) * 256 + gd) * YP + nn] = ((const short*)&v)[e];
                }
            }
        }
    }
}

// ---------------------------------------------------------------------------
// Merged tabular GEMMs (fp32): which=0 -> T_X (bias b_tx), which=1 -> T_q.
// ---------------------------------------------------------------------------
__global__ __launch_bounds__(256) void gemm_tab(
    const float* __restrict__ Atab, const float* __restrict__ Wtx,
    const float* __restrict__ btx, const float* __restrict__ Wtq,
    float* __restrict__ Ctx, float* __restrict__ Ctq)
{
    const int which = blockIdx.x >> 4;
    const float* Wm = which ? Wtq : Wtx;
    float* C = which ? Ctq : Ctx;
    __shared__ float As[16][68];
    __shared__ float Ws[16][68];
    const int tid = threadIdx.x;
    const int tx = tid & 15;
    const int ty = tid >> 4;
    const int m0 = blockIdx.y * 64;
    const int o0 = (blockIdx.x & 15) * 64;

    float acc[4][4] = {};
    for (int k0 = 0; k0 < INF_; k0 += 16) {
        const int j = tid & 15;
        const int i = tid >> 4;
        #pragma unroll
        for (int r = 0; r < 4; ++r)
            As[j][i + 16 * r] = Atab[(size_t)(m0 + i + 16 * r) * INF_ + k0 + j];
        #pragma unroll
        for (int r = 0; r < 4; ++r)
            Ws[j][i + 16 * r] = Wm[(size_t)(o0 + i + 16 * r) * INF_ + k0 + j];
        __syncthreads();
        #pragma unroll
        for (int kk = 0; kk < 16; ++kk) {
            const float4 av = *(const float4*)&As[kk][ty * 4];
            const float4 wv = *(const float4*)&Ws[kk][tx * 4];
            const float a[4] = {av.x, av.y, av.z, av.w};
            const float w[4] = {wv.x, wv.y, wv.z, wv.w};
            #pragma unroll
            for (int r = 0; r < 4; ++r)
                #pragma unroll
                for (int c = 0; c < 4; ++c)
                    acc[r][c] += a[r] * w[c];
        }
        __syncthreads();
    }
    #pragma unroll
    for (int r = 0; r < 4; ++r) {
        const int m = m0 + ty * 4 + r;
        const int o = o0 + tx * 4;
        float4 v;
        float* vp = (float*)&v;
        #pragma unroll
        for (int c = 0; c < 4; ++c) {
            float t = acc[r][c] + (which ? 0.f : btx[o + c]);
            vp[c] = LRELU(t);
        }
        *(float4*)&C[(size_t)m * OUTF + o] = v;
    }
}

// ---------------------------------------------------------------------------
// Generic fp32 tiled GEMM (final Z GEMM only).
// ---------------------------------------------------------------------------
__global__ __launch_bounds__(256) void gemm_aw(
    const float* __restrict__ A, const float* __restrict__ W,
    const float* __restrict__ bias, float* __restrict__ C,
    int M, int K, int O)
{
    __shared__ float As[16][68];
    __shared__ float Ws[16][68];
    const int tid = threadIdx.x;
    const int tx = tid & 15;
    const int ty = tid >> 4;
    const int m0 = blockIdx.y * 64;
    const int o0 = blockIdx.x * 64;

    float acc[4][4] = {};
    for (int k0 = 0; k0 < K; k0 += 16) {
        const int j = tid & 15;
        const int i = tid >> 4;
        #pragma unroll
        for (int r = 0; r < 4; ++r)
            As[j][i + 16 * r] = A[(size_t)(m0 + i + 16 * r) * K + k0 + j];
        #pragma unroll
        for (int r = 0; r < 4; ++r)
            Ws[j][i + 16 * r] = W[(size_t)(o0 + i + 16 * r) * K + k0 + j];
        __syncthreads();
        #pragma unroll
        for (int kk = 0; kk < 16; ++kk) {
            const float4 av = *(const float4*)&As[kk][ty * 4];
            const float4 wv = *(const float4*)&Ws[kk][tx * 4];
            const float a[4] = {av.x, av.y, av.z, av.w};
            const float w[4] = {wv.x, wv.y, wv.z, wv.w};
            #pragma unroll
            for (int r = 0; r < 4; ++r)
                #pragma unroll
                for (int c = 0; c < 4; ++c)
                    acc[r][c] += a[r] * w[c];
        }
        __syncthreads();
    }
    #pragma unroll
    for (int r = 0; r < 4; ++r) {
        const int m = m0 + ty * 4 + r;
        const int o = o0 + tx * 4;
        float4 v;
        float* vp = (float*)&v;
        #pragma unroll
        for (int c = 0; c < 4; ++c) {
            float t = acc[r][c] + (bias ? bias[o + c] : 0.f);
            vp[c] = LRELU(t);
        }
        *(float4*)&C[(size_t)m * O + o] = v;
    }
}

// ---------------------------------------------------------------------------
// node_att softmax: Gk at Gcat cols [0,1024), stride OC2.
// ---------------------------------------------------------------------------
__global__ __launch_bounds__(256) void nodeatt_kernel(
    const float* __restrict__ Tq, const __hip_bfloat16* __restrict__ Gcat,
    float* __restrict__ att)
{
    const int b = blockIdx.x;
    __shared__ float tq[OUTF];
    __shared__ float sc[136];
    const int tid = threadIdx.x;
    for (int o = tid; o < OUTF; o += 256) tq[o] = Tq[(size_t)b * OUTF + o];
    __syncthreads();

    const int wave = tid >> 6, lane = tid & 63;
    for (int n = wave; n < Nn; n += 4) {
        const short4* gk = (const short4*)((const short*)Gcat + ((size_t)b * Nn + n) * OC2);
        float s = 0.f;
        for (int o4 = lane; o4 < 256; o4 += 64) {
            const short4 v = gk[o4];
            s += tq[o4 * 4 + 0] * bf2f(v.x) + tq[o4 * 4 + 1] * bf2f(v.y)
               + tq[o4 * 4 + 2] * bf2f(v.z) + tq[o4 * 4 + 3] * bf2f(v.w);
        }
        #pragma unroll
        for (int off = 32; off; off >>= 1) s += __shfl_xor(s, off);
        if (lane == 0) sc[n] = s * (1.f / 32.f);
    }
    __syncthreads();

    if (tid < 64) {
        const float v1 = sc[tid];
        const float v2 = sc[tid + 64];
        const float v3 = (tid < 3) ? sc[tid + 128] : -1e30f;
        float m = fmaxf(fmaxf(v1, v2), v3);
        #pragma unroll
        for (int off = 32; off; off >>= 1) m = fmaxf(m, __shfl_xor(m, off));
        const float e1 = expf(v1 - m);
        const float e2 = expf(v2 - m);
        const float e3 = (tid < 3) ? expf(v3 - m) : 0.f;
        float s = e1 + e2 + e3;
        #pragma unroll
        for (int off = 32; off; off >>= 1) s += __shfl_xor(s, off);
        const float inv = 1.f / s;
        float* ab = att + (size_t)b * Nn;
        ab[tid] = e1 * inv + 1.f;
        ab[tid + 64] = e2 * inv + 1.f;
        if (tid < 3) ab[tid + 128] = e3 * inv + 1.f;
    }
}

// ---------------------------------------------------------------------------
// edge_agg (R14 structure): one block (9 waves) per (b,h). Gq at cols
// [1024,2048), Gk at [0,1024) of Gcat (stride OC2).
// ---------------------------------------------------------------------------
__global__ __launch_bounds__(576) void edge_agg(
    const __hip_bfloat16* __restrict__ Gcat, const float* __restrict__ adj,
    const float* __restrict__ att, const __hip_bfloat16* __restrict__ GrawT,
    const float* __restrict__ Wgs, float* __restrict__ edge,
    float* __restrict__ Gout, float* __restrict__ gnode)
{
    __shared__ short SM[25056];
    __shared__ float rsL[144 * 3];
    __shared__ float dxL[Nn], daL[Nn], attL[Nn], wgsL[Nn];

    const int bh = blockIdx.x, b = bh >> 2, h = bh & 3;
    const int tid = threadIdx.x;
    const int lane = tid & 63, wid = tid >> 6;
    const int wr = wid / 3, wc = wid % 3;
    if (tid < Nn) { attL[tid] = att[(size_t)b * Nn + tid]; wgsL[tid] = Wgs[tid]; }

    const short* qb = (const short*)Gcat + (size_t)b * Nn * OC2 + 1024 + h * Dd;
    const short* kb = (const short*)Gcat + (size_t)b * Nn * OC2 + h * Dd;
    const short* gsrcT = (const short*)GrawT + (size_t)bh * 256 * YP;

    int srow = tid >> 2; if (srow > Nn - 1) srow = Nn - 1;
    const int gsrc = ((tid & 3) ^ ((tid >> 3) & 3)) * 8;
    const int dstoff = (tid & ~63) * 8;

    auto STAGE = [&](int buf, int k0) {
        gload_lds16(qb + (size_t)srow * OC2 + k0 + gsrc, &SM[buf * 4608 + dstoff]);
        gload_lds16(kb + (size_t)srow * OC2 + k0 + gsrc, &SM[9216 + buf * 4608 + dstoff]);
    };

    f32x4 acc[3][3] = {};
    const int sa = ((lane >> 4) ^ ((lane >> 1) & 3)) * 8;

    STAGE(0, 0);
    for (int t = 0; t < 8; ++t) {
        const int buf = t & 1;
        if (t < 7) {
            STAGE(buf ^ 1, (t + 1) * 32);
            asm volatile("s_waitcnt vmcnt(2)" ::: "memory");
        } else {
            asm volatile("s_waitcnt vmcnt(0)" ::: "memory");
        }
        __builtin_amdgcn_s_barrier();
        __builtin_amdgcn_sched_barrier(0);
        bf16x8 qf[3], kf[3];
        #pragma unroll
        for (int i = 0; i < 3; ++i) {
            qf[i] = *(const bf16x8*)&SM[buf * 4608 + (wr * 48 + i * 16 + (lane & 15)) * 32 + sa];
            kf[i] = *(const bf16x8*)&SM[9216 + buf * 4608 + (wc * 48 + i * 16 + (lane & 15)) * 32 + sa];
        }
        __builtin_amdgcn_s_setprio(1);
        #pragma unroll
        for (int mi = 0; mi < 3; ++mi)
            #pragma unroll
            for (int ni = 0; ni < 3; ++ni)
                acc[mi][ni] = __builtin_amdgcn_mfma_f32_16x16x32_bf16(
                    qf[mi], kf[ni], acc[mi][ni], 0, 0, 0);
        __builtin_amdgcn_s_setprio(0);
        __builtin_amdgcn_sched_barrier(0);
        if (t < 7) __builtin_amdgcn_s_barrier();
    }

    // phase 2: adj -> regs, sigmoid, edge write, slotted rowsums
    const float* adjb = adj + (size_t)b * Nn * Nn;
    float* edgeb = edge + (size_t)bh * Nn * Nn;
    const int cc = lane & 15;
    const int rg = (lane >> 4) * 4;
    float areg[3][3][4];
    #pragma unroll
    for (int mi = 0; mi < 3; ++mi) {
        float rsum[4] = {0.f, 0.f, 0.f, 0.f};
        #pragma unroll
        for (int ni = 0; ni < 3; ++ni) {
            const int y = wc * 48 + ni * 16 + cc;
            #pragma unroll
            for (int r = 0; r < 4; ++r) {
                const int x = wr * 48 + mi * 16 + rg + r;
                const bool in = (x < Nn) && (y < Nn);
                const float a = in ? adjb[x * Nn + y] : 0.f;
                areg[mi][ni][r] = a;
                const float e = 1.f / (1.f + __expf(-acc[mi][ni][r] * (1.f / 16.f)));
                acc[mi][ni][r] = e;
                if (in) {
                    edgeb[x * Nn + y] = e;
                    rsum[r] += a * e;
                }
            }
        }
        #pragma unroll
        for (int r = 0; r < 4; ++r) {
            float v = rsum[r];
            v += __shfl_xor(v, 1); v += __shfl_xor(v, 2);
            v += __shfl_xor(v, 4); v += __shfl_xor(v, 8);
            const int x = wr * 48 + mi * 16 + rg + r;
            if (cc == 0 && x < Nn) rsL[x * 3 + wc] = v;
        }
    }
    __syncthreads();
    if (tid < Nn) {
        const float s = rsL[tid * 3] + rsL[tid * 3 + 1] + rsL[tid * 3 + 2];
        const float dv = rsqrtf(s + 1.f);
        dxL[tid] = dv;
        daL[tid] = dv * attL[tid];
    }
    __syncthreads();   // Qs/Ks dead -> SM reusable as WbL

    // phase 2b: prefetch chunk-0 B-fragments (L2-resident GrawT)
    const int brow0 = wid * 32 + (lane & 15);
    const int bcol = (lane >> 4) * 8;
    bf16x8 bcur0, bcur1;
    if (wid < 8) {
        bcur0 = *(const bf16x8*)&gsrcT[(size_t)brow0 * YP + 0 + bcol];
        bcur1 = *(const bf16x8*)&gsrcT[(size_t)(brow0 + 16) * YP + 0 + bcol];
    }

    // phase 3: Wb -> LDS (stride WLP). Zero y in [131,160).
    short* WbL = SM;
    for (int i = tid; i < 144 * 29; i += 576) {
        const int x = i / 29, y = 131 + i % 29;
        WbL[x * WLP + y] = 0;
    }
    #pragma unroll
    for (int mi = 0; mi < 3; ++mi)
        #pragma unroll
        for (int ni = 0; ni < 3; ++ni) {
            const int y = wc * 48 + ni * 16 + cc;
            #pragma unroll
            for (int r = 0; r < 4; ++r) {
                const int x = wr * 48 + mi * 16 + rg + r;
                if (x < Nn && y < Nn) {
                    float a = areg[mi][ni][r] * acc[mi][ni][r];
                    if (x == y) a += 1.f;
                    const float w = dxL[x] * a * daL[y];
                    __hip_bfloat16 hb = __float2bfloat16(w);
                    WbL[(size_t)x * WLP + y] = *(short*)&hb;
                }
            }
        }
    __syncthreads();   // WbL visible to all waves

    // phase 4: aggregation MFMA — af from WbL, bfr rolling register prefetch.
    if (wid < 8) {
        f32x4 gacc[9][2] = {};
        #pragma unroll
        for (int kc = 0; kc < 5; ++kc) {
            bf16x8 bnxt0, bnxt1;
            if (kc < 4) {
                bnxt0 = *(const bf16x8*)&gsrcT[(size_t)brow0 * YP + (kc + 1) * 32 + bcol];
                bnxt1 = *(const bf16x8*)&gsrcT[(size_t)(brow0 + 16) * YP + (kc + 1) * 32 + bcol];
            }
            bf16x8 af[9];
            #pragma unroll
            for (int mi = 0; mi < 9; ++mi)
                af[mi] = *(const bf16x8*)&WbL[(mi * 16 + (lane & 15)) * WLP + kc * 32 + (lane >> 4) * 8];
            __builtin_amdgcn_s_setprio(1);
            #pragma unroll
            for (int mi = 0; mi < 9; ++mi) {
                gacc[mi][0] = __builtin_amdgcn_mfma_f32_16x16x32_bf16(
                    af[mi], bcur0, gacc[mi][0], 0, 0, 0);
                gacc[mi][1] = __builtin_amdgcn_mfma_f32_16x16x32_bf16(
                    af[mi], bcur1, gacc[mi][1], 0, 0, 0);
            }
            __builtin_amdgcn_s_setprio(0);
            if (kc < 4) { bcur0 = bnxt0; bcur1 = bnxt1; }
        }

        // phase 5: Gout + gnode colsum (8 waves)
        float* gob = Gout + (size_t)b * Nn * OUTF + h * Dd;
        float gp[2] = {0.f, 0.f};
        #pragma unroll
        for (int mi = 0; mi < 9; ++mi)
            #pragma unroll
            for (int ni = 0; ni < 2; ++ni) {
                const int d = wid * 32 + ni * 16 + (lane & 15);
                #pragma unroll
                for (int r = 0; r < 4; ++r) {
                    const int x = mi * 16 + (lane >> 4) * 4 + r;
                    if (x < Nn) {
                        gob[(size_t)x * OUTF + d] = gacc[mi][ni][r];
                        gp[ni] += wgsL[x] * gacc[mi][ni][r];
                    }
                }
            }
        #pragma unroll
        for (int ni = 0; ni < 2; ++ni) {
            gp[ni] += __shfl_xor(gp[ni], 16);
            gp[ni] += __shfl_xor(gp[ni], 32);
            if (lane < 16)
                gnode[(size_t)b * OUTF + h * Dd + wid * 32 + ni * 16 + lane] = gp[ni];
        }
    }
}

// ---------------------------------------------------------------------------
// Zin build: Zin[b][0:1024] = lrelu(gnode + bgs), Zin[b][1024:2048] = T_X.
// ---------------------------------------------------------------------------
__global__ __launch_bounds__(256) void zin_build(
    const float* __restrict__ gnode, const float* __restrict__ bgs,
    const float* __restrict__ Tx, float* __restrict__ Zin)
{
    const int idx = blockIdx.x * 256 + threadIdx.x;
    const int b = idx >> 10, o = idx & 1023;
    const float s = gnode[idx] + bgs[0];
    Zin[(size_t)b * 2048 + o] = LRELU(s);
    Zin[(size_t)b * 2048 + 1024 + o] = Tx[idx];
}

// ---------------------------------------------------------------------------
extern "C" void kernel_launch(void* const* d_in, const int* in_sizes, int n_in,
                              void* d_out, int out_size, void* d_ws, size_t ws_size,
                              hipStream_t stream) {
    const float* tab  = (const float*)d_in[0];
    const float* node = (const float*)d_in[1];
    const float* adj  = (const float*)d_in[2];
    const float* W_gx = (const float*)d_in[3];
    const float* b_gx = (const float*)d_in[4];
    const float* W_tx = (const float*)d_in[5];
    const float* b_tx = (const float*)d_in[6];
    const float* W_gk = (const float*)d_in[7];
    const float* W_tq = (const float*)d_in[8];
    const float* W_gq = (const float*)d_in[9];
    const float* W_gs = (const float*)d_in[10];
    const float* b_gs = (const float*)d_in[11];
    const float* W_zx = (const float*)d_in[12];
    const float* b_zx = (const float*)d_in[13];

    const size_t GX_ELEMS = (size_t)Bb * Nn * OUTF;   // 34,340,864
    const int M_NODE = Bb * Nn;                       // 33536

    float* out   = (float*)d_out;
    float* o_GX  = out;
    float* o_TX  = o_GX + GX_ELEMS;
    float* o_ZX  = o_TX + (size_t)Bb * OUTF;
    float* o_ATT = o_ZX + (size_t)Bb * OUTF;
    float* o_EDG = o_ATT + (size_t)Bb * Nn;

    // workspace: bf16 regions first, then fp32
    __hip_bfloat16* wb      = (__hip_bfloat16*)d_ws;
    __hip_bfloat16* w_nodeb = wb;                                          // 33536*512
    __hip_bfloat16* w_Wcat  = w_nodeb + (size_t)M_NODE * INF_;             // 3072*512
    __hip_bfloat16* w_Gcat  = w_Wcat + (size_t)3072 * INF_;                // 33536*2048
    __hip_bfloat16* w_GrawT = w_Gcat + (size_t)M_NODE * OC2;               // 1024*256*168
    float* wf       = (float*)(w_GrawT + (size_t)Bb * Hh * 256 * YP);
    float* w_Tq     = wf;
    float* w_Zin    = w_Tq + (size_t)Bb * OUTF;
    float* w_gnode  = w_Zin + (size_t)Bb * 2 * OUTF;                       // 256*1024

    const dim3 blk(256);

    // 0. fp32 -> bf16 (Wcat = [Wgk | Wgq | Wgx])
    convert_kernel<<<dim3(2048), blk, 0, stream>>>(node, W_gx, W_gk, W_gq,
                                                   w_nodeb, w_Wcat);
    // 1. merged tabular GEMMs (T_X + T_q)
    gemm_tab<<<dim3(32, 4), blk, 0, stream>>>(tab, W_tx, b_tx, W_tq, o_TX, w_Tq);
    // 2. fused node GEMM -> Gcat [M][2048] + GrawT (transposed, coalesced)
    gemm_node_mfma<<<dim3(24, M_NODE / 128), blk, 0, stream>>>(
        w_nodeb, w_Wcat, b_gx, w_Gcat, w_GrawT);
    // 3. node attention -> o_ATT (softmax + 1)
    nodeatt_kernel<<<dim3(Bb), blk, 0, stream>>>(w_Tq, w_Gcat, o_ATT);
    // 4. fused edge attention + rowsum + dinv + Wb(LDS) + aggregation + gn
    edge_agg<<<dim3(Bb * Hh), dim3(576), 0, stream>>>(
        w_Gcat, adj, o_ATT, w_GrawT, W_gs, o_EDG, o_GX, w_gnode);
    // 5. Zin build
    zin_build<<<dim3((Bb * OUTF) / 256), blk, 0, stream>>>(w_gnode, b_gs, o_TX, w_Zin);
    // 6. final Z GEMM
    gemm_aw<<<dim3(16, 4), blk, 0, stream>>>(w_Zin, W_zx, b_zx, o_ZX, Bb, 2 * OUTF, OUTF);
}